// Round 9
// baseline (301.901 us; speedup 1.0000x reference)
//
#include <hip/hip_runtime.h>

// DepthAugmentation round 9 (ablation round):
//  - round-5 shape: 2 float4 groups/thread (cols 4c, 4c+320), 9600 blocks
//    (finer tail granularity than round 8's 4800; round 8 showed deeper MLP
//    is NEUTRAL -> per-CU memory-concurrency ceiling, not ILP).
//  - stick fused into main kernel (round 8 verified correct).
//  - ABLATION: plain loads (no nontemporal) -- tests whether nt-load flags
//    cost anything on the L2/L3 path. nt kept on stores (write-once stream).

typedef float f32x4 __attribute__((ext_vector_type(4)));

constexpr int Bc  = 64;
constexpr int Hc  = 480;
constexpr int Wc  = 640;
constexpr int HLO = 120;
constexpr int WLO = 160;
constexpr int HW  = Hc * Wc;         // 307200
constexpr int CS  = 80;              // column slots per row (2 groups/thread)

#define NOISE_SIGMA 0.005f
#define P_DROPOUT   0.003125f
#define P_RANDOM    0.003125f
#define STICK_THRESH 76.8f           // P_STICK * H * W

__device__ __forceinline__ float vlerp(const float* la, const float* lb,
                                       int col, float gy, float fy) {
    return la[col] * gy + lb[col] * fy;
}

__global__ __launch_bounds__(256) void aug_main_kernel(
    const float* __restrict__ depth,
    const float* __restrict__ noise_lo,
    const float* __restrict__ dropout_u,
    const float* __restrict__ random_u,
    const float* __restrict__ random_vals,
    const float* __restrict__ stick_u,
    const float* __restrict__ horiz_u,
    const float* __restrict__ fallback_vals,
    const int* __restrict__ stick_len,
    const int* __restrict__ stick_width,
    const int* __restrict__ stick_y,
    const int* __restrict__ stick_x,
    float* __restrict__ out)
{
    const int b = blockIdx.y;
    const int t = blockIdx.x * 256 + threadIdx.x;   // [0,38400): 150 blocks * 256
    const int y = t / CS;                           // row [0,480)
    const int c = t - y * CS;                       // slot [0,80); groups c, c+80

    // ---- vertical bilinear (half-pixel: in_y = y*0.25 - 0.375) ----
    const int r = y & 3, k = y >> 2;
    const int y0 = (r < 2) ? (k - 1) : k;
    const float fy = (r == 0) ? 0.625f : (r == 1) ? 0.875f : (r == 2) ? 0.125f : 0.375f;
    const float gy = 1.0f - fy;
    const int ya = max(y0, 0);
    const int yb = min(y0 + 1, HLO - 1);

    const size_t base = (size_t)b * HW + (size_t)y * Wc;
    const size_t iA = base + (size_t)c * 4;         // cols 4c..4c+3
    const size_t iB = iA + 320;                     // cols 4c+320..4c+323

    // ---- issue all 6 streaming loads up front (plain loads: nt ablation) ----
    const f32x4 dA = *reinterpret_cast<const f32x4*>(depth     + iA);
    const f32x4 dB = *reinterpret_cast<const f32x4*>(depth     + iB);
    const f32x4 uA = *reinterpret_cast<const f32x4*>(dropout_u + iA);
    const f32x4 uB = *reinterpret_cast<const f32x4*>(dropout_u + iB);
    const f32x4 rA = *reinterpret_cast<const f32x4*>(random_u  + iA);
    const f32x4 rB = *reinterpret_cast<const f32x4*>(random_u  + iB);

    // ---- cached noise taps (L1/L2 hits; 75KB/batch) ----
    const float* lo = noise_lo + (size_t)b * (HLO * WLO);
    const float* la = lo + ya * WLO;
    const float* lb = lo + yb * WLO;
    const float a0 = vlerp(la, lb, max(c - 1, 0), gy, fy);
    const float a1 = vlerp(la, lb, c,             gy, fy);
    const float a2 = vlerp(la, lb, c + 1,         gy, fy);
    const float b0 = vlerp(la, lb, c + 79,        gy, fy);
    const float b1 = vlerp(la, lb, c + 80,        gy, fy);
    const float b2 = vlerp(la, lb, min(c + 81, WLO - 1), gy, fy);

    // horizontal taps per (col mod 4): (lo,hi) weights (.375,.625),(.125,.875),(.875,.125),(.625,.375)
#define HN(p0, p1, p2, n0, n1, n2, n3)                          \
    const float n0 = (p0 * 0.375f + p1 * 0.625f) * NOISE_SIGMA; \
    const float n1 = (p0 * 0.125f + p1 * 0.875f) * NOISE_SIGMA; \
    const float n2 = (p1 * 0.875f + p2 * 0.125f) * NOISE_SIGMA; \
    const float n3 = (p1 * 0.625f + p2 * 0.375f) * NOISE_SIGMA;
    HN(a0, a1, a2, nA0, nA1, nA2, nA3)
    HN(b0, b1, b2, nB0, nB1, nB2, nB3)
#undef HN

    // ---- aug pipeline: noise(valid) -> clip -> dropout -> random ----
#define AUG(dv, uv, rv, n0, n1, n2, n3, idx, q0, q1, q2, q3)                  \
    float q0 = fminf(fmaxf(dv.x + (dv.x > 0.0f ? n0 : 0.0f), 0.0f), 1.0f);    \
    float q1 = fminf(fmaxf(dv.y + (dv.y > 0.0f ? n1 : 0.0f), 0.0f), 1.0f);    \
    float q2 = fminf(fmaxf(dv.z + (dv.z > 0.0f ? n2 : 0.0f), 0.0f), 1.0f);    \
    float q3 = fminf(fmaxf(dv.w + (dv.w > 0.0f ? n3 : 0.0f), 0.0f), 1.0f);    \
    if (uv.x < P_DROPOUT) q0 = 0.0f;                                          \
    if (uv.y < P_DROPOUT) q1 = 0.0f;                                          \
    if (uv.z < P_DROPOUT) q2 = 0.0f;                                          \
    if (uv.w < P_DROPOUT) q3 = 0.0f;                                          \
    if (rv.x < P_RANDOM) q0 = random_vals[idx + 0];                           \
    if (rv.y < P_RANDOM) q1 = random_vals[idx + 1];                           \
    if (rv.z < P_RANDOM) q2 = random_vals[idx + 2];                           \
    if (rv.w < P_RANDOM) q3 = random_vals[idx + 3];
    AUG(dA, uA, rA, nA0, nA1, nA2, nA3, iA, oA0, oA1, oA2, oA3)
    AUG(dB, uB, rB, nB0, nB1, nB2, nB3, iB, oB0, oB1, oB2, oB3)
#undef AUG

    // ---- stick overwrite (only rows [ry, ry+sh) of each batch) ----
    if (stick_u[b] < STICK_THRESH) {
        const bool horizontal = horiz_u[b] > 0.5f;
        const int length = stick_len[b] + 1;     // [1,18]
        const int width  = stick_width[b] + 1;   // [1,3]
        const int sh = horizontal ? width : length;
        const int sw = horizontal ? length : width;
        const int ry = min(max(stick_y[b], 0), max(Hc - sh, 1) - 1);
        const int rx = min(max(stick_x[b], 0), max(Wc - sw, 1) - 1);
        if (y >= ry && y < ry + sh) {
            // recompute aug(ry, rx) from inputs (identical math to main path)
            const size_t pi = (size_t)b * HW + (size_t)ry * Wc + rx;
            float dv = depth[pi];
            {
                const int vr = ry & 3, vk = ry >> 2;
                const int vy0 = (vr < 2) ? (vk - 1) : vk;
                const float vfy = (vr == 0) ? 0.625f : (vr == 1) ? 0.875f : (vr == 2) ? 0.125f : 0.375f;
                const int vya = max(vy0, 0), vyb = min(vy0 + 1, HLO - 1);
                const int hg = rx >> 2, hr = rx & 3;
                const int hx0 = (hr < 2) ? (hg - 1) : hg;
                const float wfx = (hr == 0) ? 0.625f : (hr == 1) ? 0.875f : (hr == 2) ? 0.125f : 0.375f;
                const int hxa = max(hx0, 0), hxb = min(hx0 + 1, WLO - 1);
                const float nlo = lo[vya * WLO + hxa] * (1.0f - vfy) + lo[vyb * WLO + hxa] * vfy;
                const float nhi = lo[vya * WLO + hxb] * (1.0f - vfy) + lo[vyb * WLO + hxb] * vfy;
                const float nz = (nlo * (1.0f - wfx) + nhi * wfx) * NOISE_SIGMA;
                dv = fminf(fmaxf(dv + (dv > 0.0f ? nz : 0.0f), 0.0f), 1.0f);
            }
            if (dropout_u[pi] < P_DROPOUT) dv = 0.0f;
            if (random_u[pi]  < P_RANDOM)  dv = random_vals[pi];
            const float val = (dv > 0.0f) ? dv : fallback_vals[b];

            const int xlo = rx, xhi = rx + sw;   // [xlo, xhi)
#define APPLY(colbase, q0, q1, q2, q3)                                \
            { const int cb = (colbase);                               \
              if (cb + 0 >= xlo && cb + 0 < xhi) q0 = val;            \
              if (cb + 1 >= xlo && cb + 1 < xhi) q1 = val;            \
              if (cb + 2 >= xlo && cb + 2 < xhi) q2 = val;            \
              if (cb + 3 >= xlo && cb + 3 < xhi) q3 = val; }
            APPLY(c * 4,        oA0, oA1, oA2, oA3)
            APPLY(c * 4 + 320,  oB0, oB1, oB2, oB3)
#undef APPLY
        }
    }

    f32x4 oA; oA.x = oA0; oA.y = oA1; oA.z = oA2; oA.w = oA3;
    f32x4 oB; oB.x = oB0; oB.y = oB1; oB.z = oB2; oB.w = oB3;
    __builtin_nontemporal_store(oA, reinterpret_cast<f32x4*>(out + iA));
    __builtin_nontemporal_store(oB, reinterpret_cast<f32x4*>(out + iB));
}

extern "C" void kernel_launch(void* const* d_in, const int* in_sizes, int n_in,
                              void* d_out, int out_size, void* d_ws, size_t ws_size,
                              hipStream_t stream) {
    const float* depth       = (const float*)d_in[0];
    const float* noise_lo    = (const float*)d_in[1];
    const float* dropout_u   = (const float*)d_in[2];
    const float* random_u    = (const float*)d_in[3];
    const float* random_vals = (const float*)d_in[4];
    const float* stick_u     = (const float*)d_in[5];
    const float* horiz_u     = (const float*)d_in[6];
    const float* fallback    = (const float*)d_in[7];
    const int*   slen        = (const int*)d_in[8];
    const int*   swid        = (const int*)d_in[9];
    const int*   sy          = (const int*)d_in[10];
    const int*   sx          = (const int*)d_in[11];
    float* out = (float*)d_out;

    dim3 grid(Hc * CS / 256, Bc);   // 150 x 64 blocks, exact cover (38400 thr/batch)
    aug_main_kernel<<<grid, 256, 0, stream>>>(depth, noise_lo, dropout_u,
                                              random_u, random_vals,
                                              stick_u, horiz_u, fallback,
                                              slen, swid, sy, sx, out);
}

// Round 10
// 280.594 us; speedup vs baseline: 1.0759x; 1.0759x over previous
//
#include <hip/hip_runtime.h>

// DepthAugmentation round 10: round-9 kernel with nontemporal RESTORED on loads.
// Ablation matrix: nt loads = 60us, plain loads = 108us (r9) -- nt is the lever;
// ILP depth 1/2/4 groups is neutral (r3/r5/r8). This is the best-known config:
// 2 float4 groups/thread + nt loads/stores + stick fused (single dispatch).

typedef float f32x4 __attribute__((ext_vector_type(4)));

constexpr int Bc  = 64;
constexpr int Hc  = 480;
constexpr int Wc  = 640;
constexpr int HLO = 120;
constexpr int WLO = 160;
constexpr int HW  = Hc * Wc;         // 307200
constexpr int CS  = 80;              // column slots per row (2 groups/thread)

#define NOISE_SIGMA 0.005f
#define P_DROPOUT   0.003125f
#define P_RANDOM    0.003125f
#define STICK_THRESH 76.8f           // P_STICK * H * W

__device__ __forceinline__ float vlerp(const float* la, const float* lb,
                                       int col, float gy, float fy) {
    return la[col] * gy + lb[col] * fy;
}

__global__ __launch_bounds__(256) void aug_main_kernel(
    const float* __restrict__ depth,
    const float* __restrict__ noise_lo,
    const float* __restrict__ dropout_u,
    const float* __restrict__ random_u,
    const float* __restrict__ random_vals,
    const float* __restrict__ stick_u,
    const float* __restrict__ horiz_u,
    const float* __restrict__ fallback_vals,
    const int* __restrict__ stick_len,
    const int* __restrict__ stick_width,
    const int* __restrict__ stick_y,
    const int* __restrict__ stick_x,
    float* __restrict__ out)
{
    const int b = blockIdx.y;
    const int t = blockIdx.x * 256 + threadIdx.x;   // [0,38400): 150 blocks * 256
    const int y = t / CS;                           // row [0,480)
    const int c = t - y * CS;                       // slot [0,80); groups c, c+80

    // ---- vertical bilinear (half-pixel: in_y = y*0.25 - 0.375) ----
    const int r = y & 3, k = y >> 2;
    const int y0 = (r < 2) ? (k - 1) : k;
    const float fy = (r == 0) ? 0.625f : (r == 1) ? 0.875f : (r == 2) ? 0.125f : 0.375f;
    const float gy = 1.0f - fy;
    const int ya = max(y0, 0);
    const int yb = min(y0 + 1, HLO - 1);

    const size_t base = (size_t)b * HW + (size_t)y * Wc;
    const size_t iA = base + (size_t)c * 4;         // cols 4c..4c+3
    const size_t iB = iA + 320;                     // cols 4c+320..4c+323

    // ---- issue all 6 streaming loads up front, nontemporal ----
    const f32x4 dA = __builtin_nontemporal_load(reinterpret_cast<const f32x4*>(depth     + iA));
    const f32x4 dB = __builtin_nontemporal_load(reinterpret_cast<const f32x4*>(depth     + iB));
    const f32x4 uA = __builtin_nontemporal_load(reinterpret_cast<const f32x4*>(dropout_u + iA));
    const f32x4 uB = __builtin_nontemporal_load(reinterpret_cast<const f32x4*>(dropout_u + iB));
    const f32x4 rA = __builtin_nontemporal_load(reinterpret_cast<const f32x4*>(random_u  + iA));
    const f32x4 rB = __builtin_nontemporal_load(reinterpret_cast<const f32x4*>(random_u  + iB));

    // ---- cached noise taps (L1/L2 hits; 75KB/batch) ----
    const float* lo = noise_lo + (size_t)b * (HLO * WLO);
    const float* la = lo + ya * WLO;
    const float* lb = lo + yb * WLO;
    const float a0 = vlerp(la, lb, max(c - 1, 0), gy, fy);
    const float a1 = vlerp(la, lb, c,             gy, fy);
    const float a2 = vlerp(la, lb, c + 1,         gy, fy);
    const float b0 = vlerp(la, lb, c + 79,        gy, fy);
    const float b1 = vlerp(la, lb, c + 80,        gy, fy);
    const float b2 = vlerp(la, lb, min(c + 81, WLO - 1), gy, fy);

    // horizontal taps per (col mod 4): (lo,hi) weights (.375,.625),(.125,.875),(.875,.125),(.625,.375)
#define HN(p0, p1, p2, n0, n1, n2, n3)                          \
    const float n0 = (p0 * 0.375f + p1 * 0.625f) * NOISE_SIGMA; \
    const float n1 = (p0 * 0.125f + p1 * 0.875f) * NOISE_SIGMA; \
    const float n2 = (p1 * 0.875f + p2 * 0.125f) * NOISE_SIGMA; \
    const float n3 = (p1 * 0.625f + p2 * 0.375f) * NOISE_SIGMA;
    HN(a0, a1, a2, nA0, nA1, nA2, nA3)
    HN(b0, b1, b2, nB0, nB1, nB2, nB3)
#undef HN

    // ---- aug pipeline: noise(valid) -> clip -> dropout -> random ----
#define AUG(dv, uv, rv, n0, n1, n2, n3, idx, q0, q1, q2, q3)                  \
    float q0 = fminf(fmaxf(dv.x + (dv.x > 0.0f ? n0 : 0.0f), 0.0f), 1.0f);    \
    float q1 = fminf(fmaxf(dv.y + (dv.y > 0.0f ? n1 : 0.0f), 0.0f), 1.0f);    \
    float q2 = fminf(fmaxf(dv.z + (dv.z > 0.0f ? n2 : 0.0f), 0.0f), 1.0f);    \
    float q3 = fminf(fmaxf(dv.w + (dv.w > 0.0f ? n3 : 0.0f), 0.0f), 1.0f);    \
    if (uv.x < P_DROPOUT) q0 = 0.0f;                                          \
    if (uv.y < P_DROPOUT) q1 = 0.0f;                                          \
    if (uv.z < P_DROPOUT) q2 = 0.0f;                                          \
    if (uv.w < P_DROPOUT) q3 = 0.0f;                                          \
    if (rv.x < P_RANDOM) q0 = random_vals[idx + 0];                           \
    if (rv.y < P_RANDOM) q1 = random_vals[idx + 1];                           \
    if (rv.z < P_RANDOM) q2 = random_vals[idx + 2];                           \
    if (rv.w < P_RANDOM) q3 = random_vals[idx + 3];
    AUG(dA, uA, rA, nA0, nA1, nA2, nA3, iA, oA0, oA1, oA2, oA3)
    AUG(dB, uB, rB, nB0, nB1, nB2, nB3, iB, oB0, oB1, oB2, oB3)
#undef AUG

    // ---- stick overwrite (only rows [ry, ry+sh) of each batch) ----
    if (stick_u[b] < STICK_THRESH) {
        const bool horizontal = horiz_u[b] > 0.5f;
        const int length = stick_len[b] + 1;     // [1,18]
        const int width  = stick_width[b] + 1;   // [1,3]
        const int sh = horizontal ? width : length;
        const int sw = horizontal ? length : width;
        const int ry = min(max(stick_y[b], 0), max(Hc - sh, 1) - 1);
        const int rx = min(max(stick_x[b], 0), max(Wc - sw, 1) - 1);
        if (y >= ry && y < ry + sh) {
            // recompute aug(ry, rx) from inputs (identical math to main path)
            const size_t pi = (size_t)b * HW + (size_t)ry * Wc + rx;
            float dv = depth[pi];
            {
                const int vr = ry & 3, vk = ry >> 2;
                const int vy0 = (vr < 2) ? (vk - 1) : vk;
                const float vfy = (vr == 0) ? 0.625f : (vr == 1) ? 0.875f : (vr == 2) ? 0.125f : 0.375f;
                const int vya = max(vy0, 0), vyb = min(vy0 + 1, HLO - 1);
                const int hg = rx >> 2, hr = rx & 3;
                const int hx0 = (hr < 2) ? (hg - 1) : hg;
                const float wfx = (hr == 0) ? 0.625f : (hr == 1) ? 0.875f : (hr == 2) ? 0.125f : 0.375f;
                const int hxa = max(hx0, 0), hxb = min(hx0 + 1, WLO - 1);
                const float nlo = lo[vya * WLO + hxa] * (1.0f - vfy) + lo[vyb * WLO + hxa] * vfy;
                const float nhi = lo[vya * WLO + hxb] * (1.0f - vfy) + lo[vyb * WLO + hxb] * vfy;
                const float nz = (nlo * (1.0f - wfx) + nhi * wfx) * NOISE_SIGMA;
                dv = fminf(fmaxf(dv + (dv > 0.0f ? nz : 0.0f), 0.0f), 1.0f);
            }
            if (dropout_u[pi] < P_DROPOUT) dv = 0.0f;
            if (random_u[pi]  < P_RANDOM)  dv = random_vals[pi];
            const float val = (dv > 0.0f) ? dv : fallback_vals[b];

            const int xlo = rx, xhi = rx + sw;   // [xlo, xhi)
#define APPLY(colbase, q0, q1, q2, q3)                                \
            { const int cb = (colbase);                               \
              if (cb + 0 >= xlo && cb + 0 < xhi) q0 = val;            \
              if (cb + 1 >= xlo && cb + 1 < xhi) q1 = val;            \
              if (cb + 2 >= xlo && cb + 2 < xhi) q2 = val;            \
              if (cb + 3 >= xlo && cb + 3 < xhi) q3 = val; }
            APPLY(c * 4,        oA0, oA1, oA2, oA3)
            APPLY(c * 4 + 320,  oB0, oB1, oB2, oB3)
#undef APPLY
        }
    }

    f32x4 oA; oA.x = oA0; oA.y = oA1; oA.z = oA2; oA.w = oA3;
    f32x4 oB; oB.x = oB0; oB.y = oB1; oB.z = oB2; oB.w = oB3;
    __builtin_nontemporal_store(oA, reinterpret_cast<f32x4*>(out + iA));
    __builtin_nontemporal_store(oB, reinterpret_cast<f32x4*>(out + iB));
}

extern "C" void kernel_launch(void* const* d_in, const int* in_sizes, int n_in,
                              void* d_out, int out_size, void* d_ws, size_t ws_size,
                              hipStream_t stream) {
    const float* depth       = (const float*)d_in[0];
    const float* noise_lo    = (const float*)d_in[1];
    const float* dropout_u   = (const float*)d_in[2];
    const float* random_u    = (const float*)d_in[3];
    const float* random_vals = (const float*)d_in[4];
    const float* stick_u     = (const float*)d_in[5];
    const float* horiz_u     = (const float*)d_in[6];
    const float* fallback    = (const float*)d_in[7];
    const int*   slen        = (const int*)d_in[8];
    const int*   swid        = (const int*)d_in[9];
    const int*   sy          = (const int*)d_in[10];
    const int*   sx          = (const int*)d_in[11];
    float* out = (float*)d_out;

    dim3 grid(Hc * CS / 256, Bc);   // 150 x 64 blocks, exact cover (38400 thr/batch)
    aug_main_kernel<<<grid, 256, 0, stream>>>(depth, noise_lo, dropout_u,
                                              random_u, random_vals,
                                              stick_u, horiz_u, fallback,
                                              slen, swid, sy, sx, out);
}